// Round 2
// baseline (1462.154 us; speedup 1.0000x reference)
//
#include <hip/hip_runtime.h>
#include <math.h>

namespace {

constexpr int N = 10000;
constexpr int K = 16;
constexpr int JT = 512;                  // j-chunk staged once per block (33 KB LDS)
constexpr int NCH = (N + JT - 1) / JT;   // 20 chunks (last = 272)
constexpr int RB = 25;                   // row tiles per (matrix, chunk)
constexpr int RPB = N / RB;              // 400 rows per block (exact)
constexpr int PAD = 4;                   // plane row stride 516 dwords -> 2-way write conflicts (free)

// ws layout (floats): [0]=sum(adj) [1]=tot_struct_unnorm [2]=tot_att_unnorm
//                     [4..20)=cluster_size[16]
// d_out: [0]=clu_loss [1..1+N)=struct [1+N..1+2N)=att [1+2N..1+3N)=sum
// Sections 1&2 are accumulated UNNORMALIZED via atomicAdd (d_out pre-zeroed);
// finalize normalizes in place and fills section 3 and the scalar.

__global__ __launch_bounds__(512, 4)
void scl_main(const float* __restrict__ adj, const float* __restrict__ att,
              const float* __restrict__ outm, float* __restrict__ ws,
              float* __restrict__ d_out) {
  __shared__ float planes[K][JT + PAD];

  const int bx = blockIdx.x;
  const int m = bx / (NCH * RB);               // 0 = adj, 1 = att
  const int rem = bx - m * (NCH * RB);
  const int chunk = rem / RB;
  const int rt = rem - chunk * RB;
  const float* __restrict__ A = m ? att : adj;
  const int wave = threadIdx.x >> 6;
  const int lane = threadIdx.x & 63;
  const int jbase = chunk * JT;
  const int clen = min(N - jbase, JT);         // multiple of 4

  // Stage output[jbase..jbase+clen) transposed into 16 per-k planes. Coalesced
  // float4 global reads; padded stride -> 2-way LDS write conflicts (free).
  for (int idx = threadIdx.x; idx < (clen << 2); idx += 512) {
    const int jj = idx >> 2, q = idx & 3;
    const float4 v = *(const float4*)(outm + (size_t)(jbase + jj) * K + (q << 2));
    planes[q * 4 + 0][jj] = v.x;
    planes[q * 4 + 1][jj] = v.y;
    planes[q * 4 + 2][jj] = v.z;
    planes[q * 4 + 3][jj] = v.w;
  }
  __syncthreads();   // the ONLY barrier in this kernel

  float tot = 0.f, rsum = 0.f;
  const int rbeg = rt * RPB;
  const int rend = rbeg + RPB;

  for (int r0 = rbeg + wave * 4; r0 + 4 <= rend; r0 += 32) {
    float acc0[K], acc1[K], acc2[K], acc3[K];
#pragma unroll
    for (int k = 0; k < K; ++k) { acc0[k] = 0.f; acc1[k] = 0.f; acc2[k] = 0.f; acc3[k] = 0.f; }
    const float* Ar = A + (size_t)r0 * N + jbase;
#pragma unroll
    for (int it = 0; it < JT / 256; ++it) {
      const int jl = (it << 8) + (lane << 2);
      if (jl < clen) {
        const float4 a0 = *(const float4*)(Ar + jl);
        const float4 a1 = *(const float4*)(Ar + N + jl);
        const float4 a2 = *(const float4*)(Ar + 2 * N + jl);
        const float4 a3 = *(const float4*)(Ar + 3 * N + jl);
        rsum += (a0.x + a0.y + a0.z + a0.w) + (a1.x + a1.y + a1.z + a1.w) +
                (a2.x + a2.y + a2.z + a2.w) + (a3.x + a3.y + a3.z + a3.w);
#pragma unroll
        for (int k = 0; k < K; ++k) {
          const float4 o = *(const float4*)&planes[k][jl];
          acc0[k] += a0.x * o.x + a0.y * o.y + a0.z * o.z + a0.w * o.w;
          acc1[k] += a1.x * o.x + a1.y * o.y + a1.z * o.z + a1.w * o.w;
          acc2[k] += a2.x * o.x + a2.y * o.y + a2.z * o.z + a2.w * o.w;
          acc3[k] += a3.x * o.x + a3.y * o.y + a3.z * o.z + a3.w * o.w;
        }
      }
    }
    // partial dot with output row, reduce across lanes, atomically accumulate
    const float* o0 = outm + (size_t)r0 * K;
    float p0 = 0.f, p1 = 0.f, p2 = 0.f, p3 = 0.f;
#pragma unroll
    for (int k = 0; k < K; ++k) {
      p0 += o0[k] * acc0[k];
      p1 += o0[K + k] * acc1[k];
      p2 += o0[2 * K + k] * acc2[k];
      p3 += o0[3 * K + k] * acc3[k];
    }
#pragma unroll
    for (int off = 32; off >= 1; off >>= 1) {
      p0 += __shfl_xor(p0, off, 64);
      p1 += __shfl_xor(p1, off, 64);
      p2 += __shfl_xor(p2, off, 64);
      p3 += __shfl_xor(p3, off, 64);
    }
    if (lane == 0) {
      float* dst = d_out + 1 + m * N + r0;
      atomicAdd(dst + 0, p0);
      atomicAdd(dst + 1, p1);
      atomicAdd(dst + 2, p2);
      atomicAdd(dst + 3, p3);
      tot += p0 + p1 + p2 + p3;
    }
  }
#pragma unroll
  for (int off = 32; off >= 1; off >>= 1) rsum += __shfl_xor(rsum, off, 64);
  if (lane == 0) {
    atomicAdd(&ws[1 + m], tot);
    if (m == 0) atomicAdd(&ws[0], rsum);
  }
}

// cluster_size[k] = sum_i out[i,k]
__global__ void scl_colsum(const float* __restrict__ outm, float* __restrict__ ws) {
  __shared__ float red[16][17];
  const int k = threadIdx.x & 15;
  const int g = threadIdx.x >> 4;
  float acc = 0.f;
  for (int r = blockIdx.x * 16 + g; r < N; r += gridDim.x * 16)
    acc += outm[(size_t)r * K + k];
  red[g][k] = acc;
  __syncthreads();
  if (threadIdx.x < 16) {
    float s = 0.f;
#pragma unroll
    for (int gg = 0; gg < 16; ++gg) s += red[gg][threadIdx.x];
    atomicAdd(&ws[4 + threadIdx.x], s);
  }
}

__global__ void scl_finalize(float* __restrict__ d_out, const float* __restrict__ ws) {
  const float inv = 1.0f / ws[0];
  const int i = blockIdx.x * blockDim.x + threadIdx.x;
  if (i < N) {
    const float su = d_out[1 + i];
    const float au = d_out[1 + N + i];
    d_out[1 + i] = -su * inv;
    d_out[1 + N + i] = -au * inv;
    d_out[1 + 2 * N + i] = -(su + au) * inv;
  }
  if (blockIdx.x == 0 && threadIdx.x == 0) {
    float cs2 = 0.f;
#pragma unroll
    for (int k = 0; k < K; ++k) cs2 += ws[4 + k] * ws[4 + k];
    const float reg = sqrtf(cs2) / (float)N * 4.0f - 1.0f;  // sqrt(K) = 4
    d_out[0] = -((ws[1] + ws[2]) * inv - reg);
  }
}

}  // namespace

extern "C" void kernel_launch(void* const* d_in, const int* in_sizes, int n_in,
                              void* d_out, int out_size, void* d_ws, size_t ws_size,
                              hipStream_t stream) {
  const float* adj  = (const float*)d_in[0];
  const float* att  = (const float*)d_in[1];
  const float* outm = (const float*)d_in[2];
  float* out = (float*)d_out;
  float* ws = (float*)d_ws;

  hipMemsetAsync(d_out, 0, (size_t)(1 + 3 * N) * sizeof(float), stream);
  hipMemsetAsync(d_ws, 0, 32 * sizeof(float), stream);
  scl_colsum<<<32, 256, 0, stream>>>(outm, ws);
  scl_main<<<2 * NCH * RB, 512, 0, stream>>>(adj, att, outm, ws, out);
  scl_finalize<<<(N + 255) / 256, 256, 0, stream>>>(out, ws);
}